// Round 4
// baseline (1066.121 us; speedup 1.0000x reference)
//
#include <hip/hip_runtime.h>
#include <hip/hip_bf16.h>

#define BSZ 2
#define LLEN 2048
#define NHEADS 32
#define HEADDIM 64
#define DSTATE 128
#define DCONV 4
#define DINNER (NHEADS * HEADDIM)                  // 2048
#define DPROJ  (2 * DINNER + 2 * DSTATE + NHEADS)  // 4384
#define Q 128                                      // scan chunk length
#define NCHUNK (LLEN / Q)                          // 16
#define XCW 2304                                   // XC row: [xv 2048 | B 128 | C 128]

__device__ __forceinline__ float sigm(float x) {
    return __builtin_amdgcn_rcpf(1.0f + __expf(-x));
}

// Robust python-int scalar read (int32 bits or float32 bits).
__device__ __forceinline__ float int_scalar(const int* p) {
    int i = *p;
    if (i >= 0 && i <= 1000000) return (float)i;
    return __int_as_float(i);
}

// ---------------------------------------------------------------------------
// Kernel 1: conv+silu for ALL 2304 conv channels -> XC row [xv|B|C], plus
// dt/dA. One block per (b,l); thread handles 8 x-channels + 1 B/C channel.
// ---------------------------------------------------------------------------
__global__ __launch_bounds__(256) void pre_kernel(
    const float* __restrict__ zx, const float* __restrict__ cw,
    const float* __restrict__ cb, const float* __restrict__ dtb,
    const float* __restrict__ alog, const float* __restrict__ dts,
    const int* __restrict__ mn_p, const int* __restrict__ mx_p,
    float* __restrict__ XC, float2* __restrict__ dtA)
{
    const int bl  = blockIdx.x;            // 0 .. B*L-1
    const int b   = bl / LLEN;
    const int l   = bl % LLEN;
    const int tid = threadIdx.x;

    // ---- x channels: 8 per thread (conv rows 0..2047, zx cols DINNER+c) ----
    {
        const int c8 = tid * 8;
        float acc[8];
        {
            float4 b0 = *(const float4*)(cb + c8);
            float4 b1 = *(const float4*)(cb + c8 + 4);
            acc[0]=b0.x; acc[1]=b0.y; acc[2]=b0.z; acc[3]=b0.w;
            acc[4]=b1.x; acc[5]=b1.y; acc[6]=b1.z; acc[7]=b1.w;
        }
        float4 w[8];
        #pragma unroll
        for (int j = 0; j < 8; j++) w[j] = *(const float4*)(cw + (size_t)(c8 + j) * 4);
        #pragma unroll
        for (int k = 0; k < DCONV; k++) {
            const int lk = l - (DCONV - 1) + k;
            if (lk >= 0) {
                const float* xr = zx + ((size_t)b * LLEN + lk) * DPROJ + DINNER + c8;
                float4 v0 = *(const float4*)xr;
                float4 v1 = *(const float4*)(xr + 4);
                const float tap[8] = {v0.x,v0.y,v0.z,v0.w,v1.x,v1.y,v1.z,v1.w};
                #pragma unroll
                for (int j = 0; j < 8; j++) {
                    const float wk = (k==0) ? w[j].x : (k==1) ? w[j].y : (k==2) ? w[j].z : w[j].w;
                    acc[j] += wk * tap[j];
                }
            }
        }
        float r[8];
        #pragma unroll
        for (int j = 0; j < 8; j++) r[j] = acc[j] * sigm(acc[j]);
        float* xo = XC + (size_t)bl * XCW + c8;
        *(float4*)xo       = make_float4(r[0], r[1], r[2], r[3]);
        *(float4*)(xo + 4) = make_float4(r[4], r[5], r[6], r[7]);
    }

    // ---- B/C channel: conv row 2048+tid, zx col 4096+tid ----
    {
        const int ch = 2048 + tid;
        float a = cb[ch];
        const float4 wv = *(const float4*)(cw + (size_t)ch * 4);
        #pragma unroll
        for (int k = 0; k < DCONV; k++) {
            const int lk = l - (DCONV - 1) + k;
            if (lk >= 0) {
                const float wk = (k==0) ? wv.x : (k==1) ? wv.y : (k==2) ? wv.z : wv.w;
                a += wk * zx[((size_t)b * LLEN + lk) * DPROJ + DINNER + ch];
            }
        }
        XC[(size_t)bl * XCW + ch] = a * sigm(a);
    }

    // ---- dt / dA ----
    if (tid < NHEADS) {
        float raw = zx[(size_t)bl * DPROJ + (DPROJ - NHEADS) + tid];
        float v   = raw * dts[tid] + dtb[tid];
        float sp  = (v > 20.0f) ? v : log1pf(__expf(v));
        float dt  = fminf(fmaxf(sp, int_scalar(mn_p)), int_scalar(mx_p));
        float A   = -__expf(alog[tid]);
        dtA[(size_t)bl * NHEADS + tid] = make_float2(dt, __expf(dt * A));
    }
}

// ---------------------------------------------------------------------------
// Kernel 2: per-chunk inclusive decay cumprod cumA[t] and chunk totals dtot.
// Q=128: each lane owns 2 consecutive t.
// ---------------------------------------------------------------------------
__global__ __launch_bounds__(64) void cum_kernel(
    const float2* __restrict__ dtA, float* __restrict__ cumA,
    float* __restrict__ dtot)
{
    const int c = blockIdx.x, h = blockIdx.y, b = blockIdx.z;
    const int lane = threadIdx.x;          // 0..63
    const float2* pd = dtA + ((size_t)(b * LLEN + c * Q + lane * 2)) * NHEADS + h;
    const float a0 = pd[0].y;
    const float a1 = pd[NHEADS].y;

    float s = a0 * a1;
    #pragma unroll
    for (int off = 1; off < 64; off <<= 1) {
        float v = __shfl_up(s, off, 64);
        if (lane >= off) s *= v;
    }
    float excl = __shfl_up(s, 1, 64);
    if (lane == 0) excl = 1.0f;

    const float c0 = excl * a0, c1 = c0 * a1;
    float* pc = cumA + ((size_t)(b * NHEADS + h) * NCHUNK + c) * Q + lane * 2;
    *(float2*)pc = make_float2(c0, c1);
    if (lane == 63) dtot[(size_t)(b * NHEADS + h) * NCHUNK + c] = c1;
}

// ---------------------------------------------------------------------------
// Phase A scan: zero-init local chunk scan.
// One block per (b,h,c). Wave: 8 p-slots x 8 n-groups; each lane owns
// p0=wave*8+pl and p0+32, 16 n each. Q=128 -> 1024 blocks = 4 waves/SIMD
// resident at VGPR<=128 (TLP is the latency-hiding mechanism).
// ---------------------------------------------------------------------------
__global__ __launch_bounds__(256, 4) void scan_kernel(
    const float* __restrict__ XC, const float2* __restrict__ dtA,
    const float* __restrict__ d_param, float* __restrict__ SA,
    float* __restrict__ out)
{
    const int c    = blockIdx.x;
    const int h    = blockIdx.y;
    const int b    = blockIdx.z;
    const int tid  = threadIdx.x;
    const int wave = tid >> 6;
    const int lane = tid & 63;
    const int ng   = lane & 7;             // n-group (low bits)
    const int pl   = lane >> 3;            // 0..7
    const int p0   = wave * 8 + pl;        // p_lo in 0..31; p_hi = p0+32
    const int n0   = ng * 16;
    const int t0   = c * Q;
    const int cx   = h * HEADDIM + p0;
    const float Dh = d_param[h];

    const float*  pB = XC + ((size_t)b * LLEN + t0) * XCW + 2048 + n0;  // C at +128
    const float*  pv = XC + ((size_t)b * LLEN + t0) * XCW + cx;         // x_hi at +32
    const float2* pd = dtA + ((size_t)b * LLEN + t0) * NHEADS + h;
    float*        pw = out + ((size_t)b * LLEN + t0) * DINNER + cx;     // hi at +32

    float stl[16], sth[16];
    #pragma unroll
    for (int j = 0; j < 16; j++) { stl[j] = 0.0f; sth[j] = 0.0f; }

    // depth-4 register ring for B,C,x,dtA (compiler may sink; TLP covers)
    float4 rb[4][4], rc[4][4];
    float  rxl[4], rxh[4];
    float2 rda[4];
    #pragma unroll
    for (int u = 0; u < 4; u++) {
        const float* r = pB + (size_t)u * XCW;
        #pragma unroll
        for (int i = 0; i < 4; i++) rb[u][i] = *(const float4*)(r + i * 4);
        #pragma unroll
        for (int i = 0; i < 4; i++) rc[u][i] = *(const float4*)(r + 128 + i * 4);
        rxl[u] = pv[(size_t)u * XCW];
        rxh[u] = pv[(size_t)u * XCW + 32];
        rda[u] = pd[(size_t)u * NHEADS];
    }
    const float*  pn  = pB + 4 * XCW;      // B/C prefetch row (t+4)
    const float*  pxn = pv + 4 * XCW;      // x prefetch row (t+4)
    const float2* pdn = pd + 4 * NHEADS;

    auto step = [&](int u) {
        float Bv[16], Cv[16];
        #pragma unroll
        for (int i = 0; i < 4; i++) {
            Bv[4*i+0]=rb[u][i].x; Bv[4*i+1]=rb[u][i].y; Bv[4*i+2]=rb[u][i].z; Bv[4*i+3]=rb[u][i].w;
            Cv[4*i+0]=rc[u][i].x; Cv[4*i+1]=rc[u][i].y; Cv[4*i+2]=rc[u][i].z; Cv[4*i+3]=rc[u][i].w;
        }
        const float  xl = rxl[u], xh = rxh[u];
        const float2 da = rda[u];

        // prefetch t+4 into slot u (unconditional; overrun lands in pad/next rows)
        #pragma unroll
        for (int i = 0; i < 4; i++) rb[u][i] = *(const float4*)(pn + i * 4);
        #pragma unroll
        for (int i = 0; i < 4; i++) rc[u][i] = *(const float4*)(pn + 128 + i * 4);
        rxl[u] = pxn[0];
        rxh[u] = pxn[32];
        rda[u] = pdn[0];
        pn += XCW; pxn += XCW; pdn += NHEADS;

        const float dAv = da.y;
        const float cl  = da.x * xl;
        const float ch  = da.x * xh;
        float al0 = 0.f, al1 = 0.f, ah0 = 0.f, ah1 = 0.f;
        #pragma unroll
        for (int j = 0; j < 8; j++) {
            stl[j] = dAv * stl[j] + cl * Bv[j];  al0 += stl[j] * Cv[j];
            sth[j] = dAv * sth[j] + ch * Bv[j];  ah0 += sth[j] * Cv[j];
        }
        #pragma unroll
        for (int j = 8; j < 16; j++) {
            stl[j] = dAv * stl[j] + cl * Bv[j];  al1 += stl[j] * Cv[j];
            sth[j] = dAv * sth[j] + ch * Bv[j];  ah1 += sth[j] * Cv[j];
        }
        float al = al0 + al1, ah = ah0 + ah1;
        al += __shfl_xor(al, 1, 64);  ah += __shfl_xor(ah, 1, 64);
        al += __shfl_xor(al, 2, 64);  ah += __shfl_xor(ah, 2, 64);
        al += __shfl_xor(al, 4, 64);  ah += __shfl_xor(ah, 4, 64);

        if (ng == 0) pw[0]  = al + Dh * xl;     // ungated y_pre, p_lo
        if (ng == 1) pw[32] = ah + Dh * xh;     // ungated y_pre, p_hi
        pw += DINNER;
    };

    for (int tb = 0; tb < Q; tb += 4) {
        step(0); step(1); step(2); step(3);
    }

    const size_t sb = ((size_t)(b * NHEADS + h) * NCHUNK + c) * (HEADDIM * DSTATE)
                    + (size_t)p0 * DSTATE + n0;
    *(float4*)(SA + sb)      = make_float4(stl[0],  stl[1],  stl[2],  stl[3]);
    *(float4*)(SA + sb + 4)  = make_float4(stl[4],  stl[5],  stl[6],  stl[7]);
    *(float4*)(SA + sb + 8)  = make_float4(stl[8],  stl[9],  stl[10], stl[11]);
    *(float4*)(SA + sb + 12) = make_float4(stl[12], stl[13], stl[14], stl[15]);
    const size_t sh = sb + (size_t)32 * DSTATE;
    *(float4*)(SA + sh)      = make_float4(sth[0],  sth[1],  sth[2],  sth[3]);
    *(float4*)(SA + sh + 4)  = make_float4(sth[4],  sth[5],  sth[6],  sth[7]);
    *(float4*)(SA + sh + 8)  = make_float4(sth[8],  sth[9],  sth[10], sth[11]);
    *(float4*)(SA + sh + 12) = make_float4(sth[12], sth[13], sth[14], sth[15]);
}

// ---------------------------------------------------------------------------
// Phase B: sequential chunk combine per (b,h). SA[c] := state ENTERING chunk c.
// Grid (NHEADS, BSZ, 4): 4 p-groups for better CU utilization.
// ---------------------------------------------------------------------------
__global__ __launch_bounds__(256) void combine_kernel(
    const float* __restrict__ init_state, const float* __restrict__ dtot,
    float* __restrict__ SA)
{
    const int h = blockIdx.x, b = blockIdx.y, pg = blockIdx.z;
    const size_t hd = (size_t)(b * NHEADS + h);
    const size_t eb = (size_t)pg * 2048 + (size_t)threadIdx.x * 8;

    const float4* pi = (const float4*)(init_state + hd * (HEADDIM * DSTATE) + eb);
    float4 r0 = pi[0], r1 = pi[1];

    for (int c = 0; c < NCHUNK; c++) {
        const float d = dtot[hd * NCHUNK + c];
        float4* ps = (float4*)(SA + (hd * NCHUNK + c) * (size_t)(HEADDIM * DSTATE) + eb);
        float4 l0 = ps[0], l1 = ps[1];
        ps[0] = r0; ps[1] = r1;
        r0.x = d * r0.x + l0.x;  r0.y = d * r0.y + l0.y;
        r0.z = d * r0.z + l0.z;  r0.w = d * r0.w + l0.w;
        r1.x = d * r1.x + l1.x;  r1.y = d * r1.y + l1.y;
        r1.z = d * r1.z + l1.z;  r1.w = d * r1.w + l1.w;
    }
}

// ---------------------------------------------------------------------------
// Phase C: cross-chunk correction as a tiled GEMM + gate epilogue.
//   corr[t,p] = (cumA[t]*C[t,:]) . Sin[p,:]   (K = DSTATE = 128)
//   out[t,p]  = (y_pre[t,p] + corr[t,p]) * silu(z[t,p])
// One block per (b,h,c): 256 threads, 4x8 register tile each (128t x 64p).
// ---------------------------------------------------------------------------
__global__ __launch_bounds__(256, 2) void gate_kernel(
    const float* __restrict__ zx, const float* __restrict__ XC,
    const float* __restrict__ cumA, const float* __restrict__ SA,
    float* __restrict__ out)
{
    __shared__ float sT[DSTATE][HEADDIM];   // Sin^T [n][p], 32 KB
    __shared__ float sC[32][Q];             // scaled C panel [k][t], 16 KB

    const int c = blockIdx.x, h = blockIdx.y, b = blockIdx.z;
    const int tid = threadIdx.x;
    const int tx = tid & 31;                // t-tile: t = tx*4 + i
    const int ty = tid >> 5;                // p-tile: p = ty*8 + j
    const size_t hd = (size_t)(b * NHEADS + h);
    const size_t row0 = (size_t)b * LLEN + c * Q;

    // ---- load Sin^T (transpose SA[p][n] -> sT[n][p]) ----
    {
        const int p  = tid >> 2;
        const int nq = (tid & 3) * 32;
        const float* ps = SA + (hd * NCHUNK + c) * (size_t)(HEADDIM * DSTATE)
                        + (size_t)p * DSTATE + nq;
        #pragma unroll
        for (int i = 0; i < 8; i++) {
            float4 v = *(const float4*)(ps + i * 4);
            const int n = nq + i * 4;
            sT[n][p] = v.x; sT[n+1][p] = v.y; sT[n+2][p] = v.z; sT[n+3][p] = v.w;
        }
    }

    float acc[4][8];
    #pragma unroll
    for (int i = 0; i < 4; i++)
        #pragma unroll
        for (int j = 0; j < 8; j++) acc[i][j] = 0.0f;

    const float* pCbase = XC + row0 * XCW + 2176;           // C columns
    const float* pcm    = cumA + (hd * NCHUNK + c) * Q;

    for (int kp = 0; kp < 4; kp++) {                        // 4 K-panels of 32
        __syncthreads();
        {   // stage cumA-scaled C panel, coalesced in groups of 8 lanes
            const int k4 = (tid & 7) * 4;
            #pragma unroll
            for (int rep = 0; rep < 4; rep++) {
                const int t = (tid >> 3) + rep * 32;
                float4 v = *(const float4*)(pCbase + (size_t)t * XCW + kp * 32 + k4);
                const float cm = pcm[t];
                sC[k4+0][t] = v.x * cm;
                sC[k4+1][t] = v.y * cm;
                sC[k4+2][t] = v.z * cm;
                sC[k4+3][t] = v.w * cm;
            }
        }
        __syncthreads();

        // software-pipelined inner product over the 32 k of this panel
        float avA[4], bvA[8], avB[4], bvB[8];
        *(float4*)&avA[0] = *(const float4*)&sC[0][tx*4];
        *(float4*)&bvA[0] = *(const float4*)&sT[kp*32][ty*8];
        *(float4*)&bvA[4] = *(const float4*)&sT[kp*32][ty*8+4];
        for (int k = 0; k < 32; k += 2) {
            *(float4*)&avB[0] = *(const float4*)&sC[k+1][tx*4];
            *(float4*)&bvB[0] = *(const float4*)&sT[kp*32+k+1][ty*8];
            *(float4*)&bvB[4] = *(const float4*)&sT[kp*32+k+1][ty*8+4];
            #pragma unroll
            for (int i = 0; i < 4; i++)
                #pragma unroll
                for (int j = 0; j < 8; j++) acc[i][j] += avA[i] * bvA[j];
            if (k + 2 < 32) {
                *(float4*)&avA[0] = *(const float4*)&sC[k+2][tx*4];
                *(float4*)&bvA[0] = *(const float4*)&sT[kp*32+k+2][ty*8];
                *(float4*)&bvA[4] = *(const float4*)&sT[kp*32+k+2][ty*8+4];
            }
            #pragma unroll
            for (int i = 0; i < 4; i++)
                #pragma unroll
                for (int j = 0; j < 8; j++) acc[i][j] += avB[i] * bvB[j];
        }
    }

    // ---- epilogue: out = (y_pre + corr) * silu(z) ----
    #pragma unroll
    for (int i = 0; i < 4; i++) {
        const int t = tx * 4 + i;
        float* po = out + (row0 + t) * (size_t)DINNER + h * HEADDIM + ty * 8;
        const float* pz = zx + (row0 + t) * (size_t)DPROJ + h * HEADDIM + ty * 8;
        float4 y0 = *(const float4*)po;
        float4 y1 = *(const float4*)(po + 4);
        float4 z0 = *(const float4*)pz;
        float4 z1 = *(const float4*)(pz + 4);
        const float yv[8] = {y0.x,y0.y,y0.z,y0.w,y1.x,y1.y,y1.z,y1.w};
        const float zv[8] = {z0.x,z0.y,z0.z,z0.w,z1.x,z1.y,z1.z,z1.w};
        float r[8];
        #pragma unroll
        for (int j = 0; j < 8; j++) {
            const float zg = zv[j] * sigm(zv[j]);
            r[j] = (yv[j] + acc[i][j]) * zg;
        }
        *(float4*)po       = make_float4(r[0], r[1], r[2], r[3]);
        *(float4*)(po + 4) = make_float4(r[4], r[5], r[6], r[7]);
    }
}

// ---------------------------------------------------------------------------
extern "C" void kernel_launch(void* const* d_in, const int* in_sizes, int n_in,
                              void* d_out, int out_size, void* d_ws, size_t ws_size,
                              hipStream_t stream) {
    const float* zxbcdt   = (const float*)d_in[0];
    const float* conv_w   = (const float*)d_in[1];
    const float* conv_b   = (const float*)d_in[2];
    const float* dt_bias  = (const float*)d_in[3];
    const float* a_log    = (const float*)d_in[4];
    const float* d_param  = (const float*)d_in[5];
    const float* dt_scale = (const float*)d_in[6];
    const float* init_st  = (const float*)d_in[7];
    const int* dt_min_p   = (const int*)d_in[11];
    const int* dt_max_p   = (const int*)d_in[12];
    float* out = (float*)d_out;

    // workspace: XC (pad +4 rows) 37.8 + dtA 1 + SA 33.5 + cumA 0.5 MiB ~= 73 MiB
    char* ws = (char*)d_ws;
    const size_t n_bl = (size_t)BSZ * LLEN;                           // 4096
    float*  XC  = (float*)ws;  ws += (n_bl + 4) * XCW * sizeof(float);
    float2* dtA = (float2*)ws; ws += n_bl * NHEADS * sizeof(float2);
    float*  SA  = (float*)ws;
    ws += (size_t)BSZ * NHEADS * NCHUNK * HEADDIM * DSTATE * sizeof(float);
    float*  dtot = (float*)ws; ws += (size_t)BSZ * NHEADS * NCHUNK * sizeof(float);
    float*  cumA = (float*)ws;
    ws += (size_t)BSZ * NHEADS * LLEN * sizeof(float);

    pre_kernel<<<dim3((unsigned)n_bl), 256, 0, stream>>>(
        zxbcdt, conv_w, conv_b, dt_bias, a_log, dt_scale,
        dt_min_p, dt_max_p, XC, dtA);

    cum_kernel<<<dim3(NCHUNK, NHEADS, BSZ), 64, 0, stream>>>(dtA, cumA, dtot);

    scan_kernel<<<dim3(NCHUNK, NHEADS, BSZ), 256, 0, stream>>>(
        XC, dtA, d_param, SA, out);

    combine_kernel<<<dim3(NHEADS, BSZ, 4), 256, 0, stream>>>(init_st, dtot, SA);

    gate_kernel<<<dim3(NCHUNK, NHEADS, BSZ), 256, 0, stream>>>(
        zxbcdt, XC, cumA, SA, out);
}

// Round 5
// 484.021 us; speedup vs baseline: 2.2026x; 2.2026x over previous
//
#include <hip/hip_runtime.h>
#include <hip/hip_bf16.h>

#define BSZ 2
#define LLEN 2048
#define NHEADS 32
#define HEADDIM 64
#define DSTATE 128
#define DCONV 4
#define DINNER (NHEADS * HEADDIM)                  // 2048
#define DPROJ  (2 * DINNER + 2 * DSTATE + NHEADS)  // 4384
#define Q 128                                      // scan chunk length
#define NCHUNK (LLEN / Q)                          // 16
#define XCW 2304                                   // XC row: [xv 2048 | B 128 | C 128]

__device__ __forceinline__ float sigm(float x) {
    return __builtin_amdgcn_rcpf(1.0f + __expf(-x));
}

// Robust python-int scalar read (int32 bits or float32 bits).
__device__ __forceinline__ float int_scalar(const int* p) {
    int i = *p;
    if (i >= 0 && i <= 1000000) return (float)i;
    return __int_as_float(i);
}

// ---------------------------------------------------------------------------
// Kernel 1: conv+silu for ALL 2304 conv channels -> XC row [xv|B|C], plus
// dt/dA. One block per (b,l); thread handles 8 x-channels + 1 B/C channel.
// ---------------------------------------------------------------------------
__global__ __launch_bounds__(256) void pre_kernel(
    const float* __restrict__ zx, const float* __restrict__ cw,
    const float* __restrict__ cb, const float* __restrict__ dtb,
    const float* __restrict__ alog, const float* __restrict__ dts,
    const int* __restrict__ mn_p, const int* __restrict__ mx_p,
    float* __restrict__ XC, float2* __restrict__ dtA)
{
    const int bl  = blockIdx.x;            // 0 .. B*L-1
    const int b   = bl / LLEN;
    const int l   = bl % LLEN;
    const int tid = threadIdx.x;

    // ---- x channels: 8 per thread (conv rows 0..2047, zx cols DINNER+c) ----
    {
        const int c8 = tid * 8;
        float acc[8];
        {
            float4 b0 = *(const float4*)(cb + c8);
            float4 b1 = *(const float4*)(cb + c8 + 4);
            acc[0]=b0.x; acc[1]=b0.y; acc[2]=b0.z; acc[3]=b0.w;
            acc[4]=b1.x; acc[5]=b1.y; acc[6]=b1.z; acc[7]=b1.w;
        }
        float4 w[8];
        #pragma unroll
        for (int j = 0; j < 8; j++) w[j] = *(const float4*)(cw + (size_t)(c8 + j) * 4);
        #pragma unroll
        for (int k = 0; k < DCONV; k++) {
            const int lk = l - (DCONV - 1) + k;
            if (lk >= 0) {
                const float* xr = zx + ((size_t)b * LLEN + lk) * DPROJ + DINNER + c8;
                float4 v0 = *(const float4*)xr;
                float4 v1 = *(const float4*)(xr + 4);
                const float tap[8] = {v0.x,v0.y,v0.z,v0.w,v1.x,v1.y,v1.z,v1.w};
                #pragma unroll
                for (int j = 0; j < 8; j++) {
                    const float wk = (k==0) ? w[j].x : (k==1) ? w[j].y : (k==2) ? w[j].z : w[j].w;
                    acc[j] += wk * tap[j];
                }
            }
        }
        float r[8];
        #pragma unroll
        for (int j = 0; j < 8; j++) r[j] = acc[j] * sigm(acc[j]);
        float* xo = XC + (size_t)bl * XCW + c8;
        *(float4*)xo       = make_float4(r[0], r[1], r[2], r[3]);
        *(float4*)(xo + 4) = make_float4(r[4], r[5], r[6], r[7]);
    }

    // ---- B/C channel: conv row 2048+tid, zx col 4096+tid ----
    {
        const int ch = 2048 + tid;
        float a = cb[ch];
        const float4 wv = *(const float4*)(cw + (size_t)ch * 4);
        #pragma unroll
        for (int k = 0; k < DCONV; k++) {
            const int lk = l - (DCONV - 1) + k;
            if (lk >= 0) {
                const float wk = (k==0) ? wv.x : (k==1) ? wv.y : (k==2) ? wv.z : wv.w;
                a += wk * zx[((size_t)b * LLEN + lk) * DPROJ + DINNER + ch];
            }
        }
        XC[(size_t)bl * XCW + ch] = a * sigm(a);
    }

    // ---- dt / dA ----
    if (tid < NHEADS) {
        float raw = zx[(size_t)bl * DPROJ + (DPROJ - NHEADS) + tid];
        float v   = raw * dts[tid] + dtb[tid];
        float sp  = (v > 20.0f) ? v : log1pf(__expf(v));
        float dt  = fminf(fmaxf(sp, int_scalar(mn_p)), int_scalar(mx_p));
        float A   = -__expf(alog[tid]);
        dtA[(size_t)bl * NHEADS + tid] = make_float2(dt, __expf(dt * A));
    }
}

// ---------------------------------------------------------------------------
// Kernel 2: per-chunk inclusive decay cumprod cumA[t] and chunk totals dtot.
// Q=128: each lane owns 2 consecutive t.
// ---------------------------------------------------------------------------
__global__ __launch_bounds__(64) void cum_kernel(
    const float2* __restrict__ dtA, float* __restrict__ cumA,
    float* __restrict__ dtot)
{
    const int c = blockIdx.x, h = blockIdx.y, b = blockIdx.z;
    const int lane = threadIdx.x;          // 0..63
    const float2* pd = dtA + ((size_t)(b * LLEN + c * Q + lane * 2)) * NHEADS + h;
    const float a0 = pd[0].y;
    const float a1 = pd[NHEADS].y;

    float s = a0 * a1;
    #pragma unroll
    for (int off = 1; off < 64; off <<= 1) {
        float v = __shfl_up(s, off, 64);
        if (lane >= off) s *= v;
    }
    float excl = __shfl_up(s, 1, 64);
    if (lane == 0) excl = 1.0f;

    const float c0 = excl * a0, c1 = c0 * a1;
    float* pc = cumA + ((size_t)(b * NHEADS + h) * NCHUNK + c) * Q + lane * 2;
    *(float2*)pc = make_float2(c0, c1);
    if (lane == 63) dtot[(size_t)(b * NHEADS + h) * NCHUNK + c] = c1;
}

// ---------------------------------------------------------------------------
// Phase A scan: zero-init local chunk scan.
// One block per (b,h,c). Wave: 8 p-slots x 8 n-groups; each lane owns
// p0=wave*8+pl and p0+32, 16 n each. Q=128 -> 1024 blocks = 4096 waves;
// at VGPR~108 (launch_bounds 256,2 -- round-3-verified, spill-free) the HW
// holds 4 waves/SIMD, doubling round 3's grid-limited 2 waves/SIMD.
// NOTE: (256,4) caps VGPR at 128 and SPILLS the ring (round 4: 4.16 GB
// scratch traffic, 862 us). Do not tighten the bound.
// ---------------------------------------------------------------------------
__global__ __launch_bounds__(256, 2) void scan_kernel(
    const float* __restrict__ XC, const float2* __restrict__ dtA,
    const float* __restrict__ d_param, float* __restrict__ SA,
    float* __restrict__ out)
{
    const int c    = blockIdx.x;
    const int h    = blockIdx.y;
    const int b    = blockIdx.z;
    const int tid  = threadIdx.x;
    const int wave = tid >> 6;
    const int lane = tid & 63;
    const int ng   = lane & 7;             // n-group (low bits)
    const int pl   = lane >> 3;            // 0..7
    const int p0   = wave * 8 + pl;        // p_lo in 0..31; p_hi = p0+32
    const int n0   = ng * 16;
    const int t0   = c * Q;
    const int cx   = h * HEADDIM + p0;
    const float Dh = d_param[h];

    const float*  pB = XC + ((size_t)b * LLEN + t0) * XCW + 2048 + n0;  // C at +128
    const float*  pv = XC + ((size_t)b * LLEN + t0) * XCW + cx;         // x_hi at +32
    const float2* pd = dtA + ((size_t)b * LLEN + t0) * NHEADS + h;
    float*        pw = out + ((size_t)b * LLEN + t0) * DINNER + cx;     // hi at +32

    float stl[16], sth[16];
    #pragma unroll
    for (int j = 0; j < 16; j++) { stl[j] = 0.0f; sth[j] = 0.0f; }

    // depth-4 register ring for B,C,x,dtA (compiler may sink; TLP covers)
    float4 rb[4][4], rc[4][4];
    float  rxl[4], rxh[4];
    float2 rda[4];
    #pragma unroll
    for (int u = 0; u < 4; u++) {
        const float* r = pB + (size_t)u * XCW;
        #pragma unroll
        for (int i = 0; i < 4; i++) rb[u][i] = *(const float4*)(r + i * 4);
        #pragma unroll
        for (int i = 0; i < 4; i++) rc[u][i] = *(const float4*)(r + 128 + i * 4);
        rxl[u] = pv[(size_t)u * XCW];
        rxh[u] = pv[(size_t)u * XCW + 32];
        rda[u] = pd[(size_t)u * NHEADS];
    }
    const float*  pn  = pB + 4 * XCW;      // B/C prefetch row (t+4)
    const float*  pxn = pv + 4 * XCW;      // x prefetch row (t+4)
    const float2* pdn = pd + 4 * NHEADS;

    auto step = [&](int u) {
        float Bv[16], Cv[16];
        #pragma unroll
        for (int i = 0; i < 4; i++) {
            Bv[4*i+0]=rb[u][i].x; Bv[4*i+1]=rb[u][i].y; Bv[4*i+2]=rb[u][i].z; Bv[4*i+3]=rb[u][i].w;
            Cv[4*i+0]=rc[u][i].x; Cv[4*i+1]=rc[u][i].y; Cv[4*i+2]=rc[u][i].z; Cv[4*i+3]=rc[u][i].w;
        }
        const float  xl = rxl[u], xh = rxh[u];
        const float2 da = rda[u];

        // prefetch t+4 into slot u (unconditional; overrun lands in pad rows)
        #pragma unroll
        for (int i = 0; i < 4; i++) rb[u][i] = *(const float4*)(pn + i * 4);
        #pragma unroll
        for (int i = 0; i < 4; i++) rc[u][i] = *(const float4*)(pn + 128 + i * 4);
        rxl[u] = pxn[0];
        rxh[u] = pxn[32];
        rda[u] = pdn[0];
        pn += XCW; pxn += XCW; pdn += NHEADS;

        const float dAv = da.y;
        const float cl  = da.x * xl;
        const float ch  = da.x * xh;
        float al0 = 0.f, al1 = 0.f, ah0 = 0.f, ah1 = 0.f;
        #pragma unroll
        for (int j = 0; j < 8; j++) {
            stl[j] = dAv * stl[j] + cl * Bv[j];  al0 += stl[j] * Cv[j];
            sth[j] = dAv * sth[j] + ch * Bv[j];  ah0 += sth[j] * Cv[j];
        }
        #pragma unroll
        for (int j = 8; j < 16; j++) {
            stl[j] = dAv * stl[j] + cl * Bv[j];  al1 += stl[j] * Cv[j];
            sth[j] = dAv * sth[j] + ch * Bv[j];  ah1 += sth[j] * Cv[j];
        }
        float al = al0 + al1, ah = ah0 + ah1;
        al += __shfl_xor(al, 1, 64);  ah += __shfl_xor(ah, 1, 64);
        al += __shfl_xor(al, 2, 64);  ah += __shfl_xor(ah, 2, 64);
        al += __shfl_xor(al, 4, 64);  ah += __shfl_xor(ah, 4, 64);

        if (ng == 0) pw[0]  = al + Dh * xl;     // ungated y_pre, p_lo
        if (ng == 1) pw[32] = ah + Dh * xh;     // ungated y_pre, p_hi
        pw += DINNER;
    };

    for (int tb = 0; tb < Q; tb += 4) {
        step(0); step(1); step(2); step(3);
    }

    const size_t sb = ((size_t)(b * NHEADS + h) * NCHUNK + c) * (HEADDIM * DSTATE)
                    + (size_t)p0 * DSTATE + n0;
    *(float4*)(SA + sb)      = make_float4(stl[0],  stl[1],  stl[2],  stl[3]);
    *(float4*)(SA + sb + 4)  = make_float4(stl[4],  stl[5],  stl[6],  stl[7]);
    *(float4*)(SA + sb + 8)  = make_float4(stl[8],  stl[9],  stl[10], stl[11]);
    *(float4*)(SA + sb + 12) = make_float4(stl[12], stl[13], stl[14], stl[15]);
    const size_t sh = sb + (size_t)32 * DSTATE;
    *(float4*)(SA + sh)      = make_float4(sth[0],  sth[1],  sth[2],  sth[3]);
    *(float4*)(SA + sh + 4)  = make_float4(sth[4],  sth[5],  sth[6],  sth[7]);
    *(float4*)(SA + sh + 8)  = make_float4(sth[8],  sth[9],  sth[10], sth[11]);
    *(float4*)(SA + sh + 12) = make_float4(sth[12], sth[13], sth[14], sth[15]);
}

// ---------------------------------------------------------------------------
// Phase B: sequential chunk combine per (b,h). SA[c] := state ENTERING chunk c.
// Grid (NHEADS, BSZ, 4): 4 p-groups for better CU utilization.
// ---------------------------------------------------------------------------
__global__ __launch_bounds__(256) void combine_kernel(
    const float* __restrict__ init_state, const float* __restrict__ dtot,
    float* __restrict__ SA)
{
    const int h = blockIdx.x, b = blockIdx.y, pg = blockIdx.z;
    const size_t hd = (size_t)(b * NHEADS + h);
    const size_t eb = (size_t)pg * 2048 + (size_t)threadIdx.x * 8;

    const float4* pi = (const float4*)(init_state + hd * (HEADDIM * DSTATE) + eb);
    float4 r0 = pi[0], r1 = pi[1];

    for (int c = 0; c < NCHUNK; c++) {
        const float d = dtot[hd * NCHUNK + c];
        float4* ps = (float4*)(SA + (hd * NCHUNK + c) * (size_t)(HEADDIM * DSTATE) + eb);
        float4 l0 = ps[0], l1 = ps[1];
        ps[0] = r0; ps[1] = r1;
        r0.x = d * r0.x + l0.x;  r0.y = d * r0.y + l0.y;
        r0.z = d * r0.z + l0.z;  r0.w = d * r0.w + l0.w;
        r1.x = d * r1.x + l1.x;  r1.y = d * r1.y + l1.y;
        r1.z = d * r1.z + l1.z;  r1.w = d * r1.w + l1.w;
    }
}

// ---------------------------------------------------------------------------
// Phase C: cross-chunk correction as a tiled GEMM + gate epilogue.
//   corr[t,p] = (cumA[t]*C[t,:]) . Sin[p,:]   (K = DSTATE = 128)
//   out[t,p]  = (y_pre[t,p] + corr[t,p]) * silu(z[t,p])
// One block per (b,h,c): 256 threads, 4x8 register tile each (128t x 64p).
// ---------------------------------------------------------------------------
__global__ __launch_bounds__(256, 2) void gate_kernel(
    const float* __restrict__ zx, const float* __restrict__ XC,
    const float* __restrict__ cumA, const float* __restrict__ SA,
    float* __restrict__ out)
{
    __shared__ float sT[DSTATE][HEADDIM];   // Sin^T [n][p], 32 KB
    __shared__ float sC[32][Q];             // scaled C panel [k][t], 16 KB

    const int c = blockIdx.x, h = blockIdx.y, b = blockIdx.z;
    const int tid = threadIdx.x;
    const int tx = tid & 31;                // t-tile: t = tx*4 + i
    const int ty = tid >> 5;                // p-tile: p = ty*8 + j
    const size_t hd = (size_t)(b * NHEADS + h);
    const size_t row0 = (size_t)b * LLEN + c * Q;

    // ---- load Sin^T (transpose SA[p][n] -> sT[n][p]) ----
    {
        const int p  = tid >> 2;
        const int nq = (tid & 3) * 32;
        const float* ps = SA + (hd * NCHUNK + c) * (size_t)(HEADDIM * DSTATE)
                        + (size_t)p * DSTATE + nq;
        #pragma unroll
        for (int i = 0; i < 8; i++) {
            float4 v = *(const float4*)(ps + i * 4);
            const int n = nq + i * 4;
            sT[n][p] = v.x; sT[n+1][p] = v.y; sT[n+2][p] = v.z; sT[n+3][p] = v.w;
        }
    }

    float acc[4][8];
    #pragma unroll
    for (int i = 0; i < 4; i++)
        #pragma unroll
        for (int j = 0; j < 8; j++) acc[i][j] = 0.0f;

    const float* pCbase = XC + row0 * XCW + 2176;           // C columns
    const float* pcm    = cumA + (hd * NCHUNK + c) * Q;

    for (int kp = 0; kp < 4; kp++) {                        // 4 K-panels of 32
        __syncthreads();
        {   // stage cumA-scaled C panel, coalesced in groups of 8 lanes
            const int k4 = (tid & 7) * 4;
            #pragma unroll
            for (int rep = 0; rep < 4; rep++) {
                const int t = (tid >> 3) + rep * 32;
                float4 v = *(const float4*)(pCbase + (size_t)t * XCW + kp * 32 + k4);
                const float cm = pcm[t];
                sC[k4+0][t] = v.x * cm;
                sC[k4+1][t] = v.y * cm;
                sC[k4+2][t] = v.z * cm;
                sC[k4+3][t] = v.w * cm;
            }
        }
        __syncthreads();

        // software-pipelined inner product over the 32 k of this panel
        float avA[4], bvA[8], avB[4], bvB[8];
        *(float4*)&avA[0] = *(const float4*)&sC[0][tx*4];
        *(float4*)&bvA[0] = *(const float4*)&sT[kp*32][ty*8];
        *(float4*)&bvA[4] = *(const float4*)&sT[kp*32][ty*8+4];
        for (int k = 0; k < 32; k += 2) {
            *(float4*)&avB[0] = *(const float4*)&sC[k+1][tx*4];
            *(float4*)&bvB[0] = *(const float4*)&sT[kp*32+k+1][ty*8];
            *(float4*)&bvB[4] = *(const float4*)&sT[kp*32+k+1][ty*8+4];
            #pragma unroll
            for (int i = 0; i < 4; i++)
                #pragma unroll
                for (int j = 0; j < 8; j++) acc[i][j] += avA[i] * bvA[j];
            if (k + 2 < 32) {
                *(float4*)&avA[0] = *(const float4*)&sC[k+2][tx*4];
                *(float4*)&bvA[0] = *(const float4*)&sT[kp*32+k+2][ty*8];
                *(float4*)&bvA[4] = *(const float4*)&sT[kp*32+k+2][ty*8+4];
            }
            #pragma unroll
            for (int i = 0; i < 4; i++)
                #pragma unroll
                for (int j = 0; j < 8; j++) acc[i][j] += avB[i] * bvB[j];
        }
    }

    // ---- epilogue: out = (y_pre + corr) * silu(z) ----
    #pragma unroll
    for (int i = 0; i < 4; i++) {
        const int t = tx * 4 + i;
        float* po = out + (row0 + t) * (size_t)DINNER + h * HEADDIM + ty * 8;
        const float* pz = zx + (row0 + t) * (size_t)DPROJ + h * HEADDIM + ty * 8;
        float4 y0 = *(const float4*)po;
        float4 y1 = *(const float4*)(po + 4);
        float4 z0 = *(const float4*)pz;
        float4 z1 = *(const float4*)(pz + 4);
        const float yv[8] = {y0.x,y0.y,y0.z,y0.w,y1.x,y1.y,y1.z,y1.w};
        const float zv[8] = {z0.x,z0.y,z0.z,z0.w,z1.x,z1.y,z1.z,z1.w};
        float r[8];
        #pragma unroll
        for (int j = 0; j < 8; j++) {
            const float zg = zv[j] * sigm(zv[j]);
            r[j] = (yv[j] + acc[i][j]) * zg;
        }
        *(float4*)po       = make_float4(r[0], r[1], r[2], r[3]);
        *(float4*)(po + 4) = make_float4(r[4], r[5], r[6], r[7]);
    }
}

// ---------------------------------------------------------------------------
extern "C" void kernel_launch(void* const* d_in, const int* in_sizes, int n_in,
                              void* d_out, int out_size, void* d_ws, size_t ws_size,
                              hipStream_t stream) {
    const float* zxbcdt   = (const float*)d_in[0];
    const float* conv_w   = (const float*)d_in[1];
    const float* conv_b   = (const float*)d_in[2];
    const float* dt_bias  = (const float*)d_in[3];
    const float* a_log    = (const float*)d_in[4];
    const float* d_param  = (const float*)d_in[5];
    const float* dt_scale = (const float*)d_in[6];
    const float* init_st  = (const float*)d_in[7];
    const int* dt_min_p   = (const int*)d_in[11];
    const int* dt_max_p   = (const int*)d_in[12];
    float* out = (float*)d_out;

    // workspace: XC (pad +4 rows) 37.8 + dtA 1 + SA 33.5 + cumA 0.5 MiB ~= 73 MiB
    char* ws = (char*)d_ws;
    const size_t n_bl = (size_t)BSZ * LLEN;                           // 4096
    float*  XC  = (float*)ws;  ws += (n_bl + 4) * XCW * sizeof(float);
    float2* dtA = (float2*)ws; ws += n_bl * NHEADS * sizeof(float2);
    float*  SA  = (float*)ws;
    ws += (size_t)BSZ * NHEADS * NCHUNK * HEADDIM * DSTATE * sizeof(float);
    float*  dtot = (float*)ws; ws += (size_t)BSZ * NHEADS * NCHUNK * sizeof(float);
    float*  cumA = (float*)ws;
    ws += (size_t)BSZ * NHEADS * LLEN * sizeof(float);

    pre_kernel<<<dim3((unsigned)n_bl), 256, 0, stream>>>(
        zxbcdt, conv_w, conv_b, dt_bias, a_log, dt_scale,
        dt_min_p, dt_max_p, XC, dtA);

    cum_kernel<<<dim3(NCHUNK, NHEADS, BSZ), 64, 0, stream>>>(dtA, cumA, dtot);

    scan_kernel<<<dim3(NCHUNK, NHEADS, BSZ), 256, 0, stream>>>(
        XC, dtA, d_param, SA, out);

    combine_kernel<<<dim3(NHEADS, BSZ, 4), 256, 0, stream>>>(init_st, dtot, SA);

    gate_kernel<<<dim3(NCHUNK, NHEADS, BSZ), 256, 0, stream>>>(
        zxbcdt, XC, cumA, SA, out);
}

// Round 6
// 477.368 us; speedup vs baseline: 2.2333x; 1.0139x over previous
//
#include <hip/hip_runtime.h>
#include <hip/hip_bf16.h>

#define BSZ 2
#define LLEN 2048
#define NHEADS 32
#define HEADDIM 64
#define DSTATE 128
#define DCONV 4
#define DINNER (NHEADS * HEADDIM)                  // 2048
#define DPROJ  (2 * DINNER + 2 * DSTATE + NHEADS)  // 4384
#define Q 128                                      // scan chunk length
#define NCHUNK (LLEN / Q)                          // 16
#define XCW 2304                                   // XC row: [xv 2048 | B 128 | C 128]

__device__ __forceinline__ float sigm(float x) {
    return __builtin_amdgcn_rcpf(1.0f + __expf(-x));
}

// Robust python-int scalar read (int32 bits or float32 bits).
__device__ __forceinline__ float int_scalar(const int* p) {
    int i = *p;
    if (i >= 0 && i <= 1000000) return (float)i;
    return __int_as_float(i);
}

// ---------------------------------------------------------------------------
// Kernel 1: conv+silu for ALL 2304 conv channels -> XC row [xv|B|C], plus
// dt/dA. One block per (b,l); thread handles 8 x-channels + 1 B/C channel.
// ---------------------------------------------------------------------------
__global__ __launch_bounds__(256) void pre_kernel(
    const float* __restrict__ zx, const float* __restrict__ cw,
    const float* __restrict__ cb, const float* __restrict__ dtb,
    const float* __restrict__ alog, const float* __restrict__ dts,
    const int* __restrict__ mn_p, const int* __restrict__ mx_p,
    float* __restrict__ XC, float2* __restrict__ dtA)
{
    const int bl  = blockIdx.x;            // 0 .. B*L-1
    const int b   = bl / LLEN;
    const int l   = bl % LLEN;
    const int tid = threadIdx.x;

    // ---- x channels: 8 per thread (conv rows 0..2047, zx cols DINNER+c) ----
    {
        const int c8 = tid * 8;
        float acc[8];
        {
            float4 b0 = *(const float4*)(cb + c8);
            float4 b1 = *(const float4*)(cb + c8 + 4);
            acc[0]=b0.x; acc[1]=b0.y; acc[2]=b0.z; acc[3]=b0.w;
            acc[4]=b1.x; acc[5]=b1.y; acc[6]=b1.z; acc[7]=b1.w;
        }
        float4 w[8];
        #pragma unroll
        for (int j = 0; j < 8; j++) w[j] = *(const float4*)(cw + (size_t)(c8 + j) * 4);
        #pragma unroll
        for (int k = 0; k < DCONV; k++) {
            const int lk = l - (DCONV - 1) + k;
            if (lk >= 0) {
                const float* xr = zx + ((size_t)b * LLEN + lk) * DPROJ + DINNER + c8;
                float4 v0 = *(const float4*)xr;
                float4 v1 = *(const float4*)(xr + 4);
                const float tap[8] = {v0.x,v0.y,v0.z,v0.w,v1.x,v1.y,v1.z,v1.w};
                #pragma unroll
                for (int j = 0; j < 8; j++) {
                    const float wk = (k==0) ? w[j].x : (k==1) ? w[j].y : (k==2) ? w[j].z : w[j].w;
                    acc[j] += wk * tap[j];
                }
            }
        }
        float r[8];
        #pragma unroll
        for (int j = 0; j < 8; j++) r[j] = acc[j] * sigm(acc[j]);
        float* xo = XC + (size_t)bl * XCW + c8;
        *(float4*)xo       = make_float4(r[0], r[1], r[2], r[3]);
        *(float4*)(xo + 4) = make_float4(r[4], r[5], r[6], r[7]);
    }

    // ---- B/C channel: conv row 2048+tid, zx col 4096+tid ----
    {
        const int ch = 2048 + tid;
        float a = cb[ch];
        const float4 wv = *(const float4*)(cw + (size_t)ch * 4);
        #pragma unroll
        for (int k = 0; k < DCONV; k++) {
            const int lk = l - (DCONV - 1) + k;
            if (lk >= 0) {
                const float wk = (k==0) ? wv.x : (k==1) ? wv.y : (k==2) ? wv.z : wv.w;
                a += wk * zx[((size_t)b * LLEN + lk) * DPROJ + DINNER + ch];
            }
        }
        XC[(size_t)bl * XCW + ch] = a * sigm(a);
    }

    // ---- dt / dA ----
    if (tid < NHEADS) {
        float raw = zx[(size_t)bl * DPROJ + (DPROJ - NHEADS) + tid];
        float v   = raw * dts[tid] + dtb[tid];
        float sp  = (v > 20.0f) ? v : log1pf(__expf(v));
        float dt  = fminf(fmaxf(sp, int_scalar(mn_p)), int_scalar(mx_p));
        float A   = -__expf(alog[tid]);
        dtA[(size_t)bl * NHEADS + tid] = make_float2(dt, __expf(dt * A));
    }
}

// ---------------------------------------------------------------------------
// Kernel 2: per-chunk inclusive decay cumprod cumA[t] and chunk totals dtot.
// Q=128: each lane owns 2 consecutive t.
// ---------------------------------------------------------------------------
__global__ __launch_bounds__(64) void cum_kernel(
    const float2* __restrict__ dtA, float* __restrict__ cumA,
    float* __restrict__ dtot)
{
    const int c = blockIdx.x, h = blockIdx.y, b = blockIdx.z;
    const int lane = threadIdx.x;          // 0..63
    const float2* pd = dtA + ((size_t)(b * LLEN + c * Q + lane * 2)) * NHEADS + h;
    const float a0 = pd[0].y;
    const float a1 = pd[NHEADS].y;

    float s = a0 * a1;
    #pragma unroll
    for (int off = 1; off < 64; off <<= 1) {
        float v = __shfl_up(s, off, 64);
        if (lane >= off) s *= v;
    }
    float excl = __shfl_up(s, 1, 64);
    if (lane == 0) excl = 1.0f;

    const float c0 = excl * a0, c1 = c0 * a1;
    float* pc = cumA + ((size_t)(b * NHEADS + h) * NCHUNK + c) * Q + lane * 2;
    *(float2*)pc = make_float2(c0, c1);
    if (lane == 63) dtot[(size_t)(b * NHEADS + h) * NCHUNK + c] = c1;
}

// ---------------------------------------------------------------------------
// Phase A scan: zero-init local chunk scan.
// One block per (b,h,c). Wave: 8 p-slots x 8 n-groups; each lane owns
// p0=wave*8+pl and p0+32, 16 n each. Q=128 -> 1024 blocks = 4 blocks/CU.
// __launch_bounds__(256,4): empirically (rounds 0-5) runtime residency
// tracks this second arg; (256,2) pinned us at 2 waves/SIMD regardless of
// VGPR headroom. Depth-2 ring keeps demand ~117 regs, under the 128-reg /
// 4-wave budget (round 4's depth-4 ring at ~190 demand spilled; round 2's
// ~96 demand at (256,4) compiled spill-free). If WRITE_SIZE balloons past
// ~100 MB, the allocator spilled again -> revert.
// ---------------------------------------------------------------------------
__global__ __launch_bounds__(256, 4) void scan_kernel(
    const float* __restrict__ XC, const float2* __restrict__ dtA,
    const float* __restrict__ d_param, float* __restrict__ SA,
    float* __restrict__ out)
{
    const int c    = blockIdx.x;
    const int h    = blockIdx.y;
    const int b    = blockIdx.z;
    const int tid  = threadIdx.x;
    const int wave = tid >> 6;
    const int lane = tid & 63;
    const int ng   = lane & 7;             // n-group (low bits)
    const int pl   = lane >> 3;            // 0..7
    const int p0   = wave * 8 + pl;        // p_lo in 0..31; p_hi = p0+32
    const int n0   = ng * 16;
    const int t0   = c * Q;
    const int cx   = h * HEADDIM + p0;
    const float Dh = d_param[h];

    const float*  pB = XC + ((size_t)b * LLEN + t0) * XCW + 2048 + n0;  // C at +128
    const float*  pv = XC + ((size_t)b * LLEN + t0) * XCW + cx;         // x_hi at +32
    const float2* pd = dtA + ((size_t)b * LLEN + t0) * NHEADS + h;
    float*        pw = out + ((size_t)b * LLEN + t0) * DINNER + cx;     // hi at +32

    float stl[16], sth[16];
    #pragma unroll
    for (int j = 0; j < 16; j++) { stl[j] = 0.0f; sth[j] = 0.0f; }

    // depth-2 register ring for B,C,x,dtA
    float4 rb[2][4], rc[2][4];
    float  rxl[2], rxh[2];
    float2 rda[2];
    #pragma unroll
    for (int u = 0; u < 2; u++) {
        const float* r = pB + (size_t)u * XCW;
        #pragma unroll
        for (int i = 0; i < 4; i++) rb[u][i] = *(const float4*)(r + i * 4);
        #pragma unroll
        for (int i = 0; i < 4; i++) rc[u][i] = *(const float4*)(r + 128 + i * 4);
        rxl[u] = pv[(size_t)u * XCW];
        rxh[u] = pv[(size_t)u * XCW + 32];
        rda[u] = pd[(size_t)u * NHEADS];
    }
    const float*  pn  = pB + 2 * XCW;      // B/C prefetch row (t+2)
    const float*  pxn = pv + 2 * XCW;      // x prefetch row (t+2)
    const float2* pdn = pd + 2 * NHEADS;

    auto step = [&](int u) {
        float Bv[16], Cv[16];
        #pragma unroll
        for (int i = 0; i < 4; i++) {
            Bv[4*i+0]=rb[u][i].x; Bv[4*i+1]=rb[u][i].y; Bv[4*i+2]=rb[u][i].z; Bv[4*i+3]=rb[u][i].w;
            Cv[4*i+0]=rc[u][i].x; Cv[4*i+1]=rc[u][i].y; Cv[4*i+2]=rc[u][i].z; Cv[4*i+3]=rc[u][i].w;
        }
        const float  xl = rxl[u], xh = rxh[u];
        const float2 da = rda[u];

        // prefetch t+2 into slot u (unconditional; overrun lands in pad rows)
        #pragma unroll
        for (int i = 0; i < 4; i++) rb[u][i] = *(const float4*)(pn + i * 4);
        #pragma unroll
        for (int i = 0; i < 4; i++) rc[u][i] = *(const float4*)(pn + 128 + i * 4);
        rxl[u] = pxn[0];
        rxh[u] = pxn[32];
        rda[u] = pdn[0];
        pn += XCW; pxn += XCW; pdn += NHEADS;

        const float dAv = da.y;
        const float cl  = da.x * xl;
        const float ch  = da.x * xh;
        float al0 = 0.f, al1 = 0.f, ah0 = 0.f, ah1 = 0.f;
        #pragma unroll
        for (int j = 0; j < 8; j++) {
            stl[j] = dAv * stl[j] + cl * Bv[j];  al0 += stl[j] * Cv[j];
            sth[j] = dAv * sth[j] + ch * Bv[j];  ah0 += sth[j] * Cv[j];
        }
        #pragma unroll
        for (int j = 8; j < 16; j++) {
            stl[j] = dAv * stl[j] + cl * Bv[j];  al1 += stl[j] * Cv[j];
            sth[j] = dAv * sth[j] + ch * Bv[j];  ah1 += sth[j] * Cv[j];
        }
        float al = al0 + al1, ah = ah0 + ah1;
        al += __shfl_xor(al, 1, 64);  ah += __shfl_xor(ah, 1, 64);
        al += __shfl_xor(al, 2, 64);  ah += __shfl_xor(ah, 2, 64);
        al += __shfl_xor(al, 4, 64);  ah += __shfl_xor(ah, 4, 64);

        if (ng == 0) pw[0]  = al + Dh * xl;     // ungated y_pre, p_lo
        if (ng == 1) pw[32] = ah + Dh * xh;     // ungated y_pre, p_hi
        pw += DINNER;
    };

    for (int tb = 0; tb < Q; tb += 2) {
        step(0); step(1);
    }

    const size_t sb = ((size_t)(b * NHEADS + h) * NCHUNK + c) * (HEADDIM * DSTATE)
                    + (size_t)p0 * DSTATE + n0;
    *(float4*)(SA + sb)      = make_float4(stl[0],  stl[1],  stl[2],  stl[3]);
    *(float4*)(SA + sb + 4)  = make_float4(stl[4],  stl[5],  stl[6],  stl[7]);
    *(float4*)(SA + sb + 8)  = make_float4(stl[8],  stl[9],  stl[10], stl[11]);
    *(float4*)(SA + sb + 12) = make_float4(stl[12], stl[13], stl[14], stl[15]);
    const size_t sh = sb + (size_t)32 * DSTATE;
    *(float4*)(SA + sh)      = make_float4(sth[0],  sth[1],  sth[2],  sth[3]);
    *(float4*)(SA + sh + 4)  = make_float4(sth[4],  sth[5],  sth[6],  sth[7]);
    *(float4*)(SA + sh + 8)  = make_float4(sth[8],  sth[9],  sth[10], sth[11]);
    *(float4*)(SA + sh + 12) = make_float4(sth[12], sth[13], sth[14], sth[15]);
}

// ---------------------------------------------------------------------------
// Phase B: sequential chunk combine per (b,h). SA[c] := state ENTERING chunk c.
// Grid (NHEADS, BSZ, 4): 4 p-groups for better CU utilization.
// ---------------------------------------------------------------------------
__global__ __launch_bounds__(256) void combine_kernel(
    const float* __restrict__ init_state, const float* __restrict__ dtot,
    float* __restrict__ SA)
{
    const int h = blockIdx.x, b = blockIdx.y, pg = blockIdx.z;
    const size_t hd = (size_t)(b * NHEADS + h);
    const size_t eb = (size_t)pg * 2048 + (size_t)threadIdx.x * 8;

    const float4* pi = (const float4*)(init_state + hd * (HEADDIM * DSTATE) + eb);
    float4 r0 = pi[0], r1 = pi[1];

    for (int c = 0; c < NCHUNK; c++) {
        const float d = dtot[hd * NCHUNK + c];
        float4* ps = (float4*)(SA + (hd * NCHUNK + c) * (size_t)(HEADDIM * DSTATE) + eb);
        float4 l0 = ps[0], l1 = ps[1];
        ps[0] = r0; ps[1] = r1;
        r0.x = d * r0.x + l0.x;  r0.y = d * r0.y + l0.y;
        r0.z = d * r0.z + l0.z;  r0.w = d * r0.w + l0.w;
        r1.x = d * r1.x + l1.x;  r1.y = d * r1.y + l1.y;
        r1.z = d * r1.z + l1.z;  r1.w = d * r1.w + l1.w;
    }
}

// ---------------------------------------------------------------------------
// Phase C: cross-chunk correction as a tiled GEMM + gate epilogue.
//   corr[t,p] = (cumA[t]*C[t,:]) . Sin[p,:]   (K = DSTATE = 128)
//   out[t,p]  = (y_pre[t,p] + corr[t,p]) * silu(z[t,p])
// One block per (b,h,c): 256 threads, 4x8 register tile each (128t x 64p).
// LDS 48 KB -> 3 blocks/CU; launch_bounds(256,3) to claim that residency.
// ---------------------------------------------------------------------------
__global__ __launch_bounds__(256, 3) void gate_kernel(
    const float* __restrict__ zx, const float* __restrict__ XC,
    const float* __restrict__ cumA, const float* __restrict__ SA,
    float* __restrict__ out)
{
    __shared__ float sT[DSTATE][HEADDIM];   // Sin^T [n][p], 32 KB
    __shared__ float sC[32][Q];             // scaled C panel [k][t], 16 KB

    const int c = blockIdx.x, h = blockIdx.y, b = blockIdx.z;
    const int tid = threadIdx.x;
    const int tx = tid & 31;                // t-tile: t = tx*4 + i
    const int ty = tid >> 5;                // p-tile: p = ty*8 + j
    const size_t hd = (size_t)(b * NHEADS + h);
    const size_t row0 = (size_t)b * LLEN + c * Q;

    // ---- load Sin^T (transpose SA[p][n] -> sT[n][p]) ----
    {
        const int p  = tid >> 2;
        const int nq = (tid & 3) * 32;
        const float* ps = SA + (hd * NCHUNK + c) * (size_t)(HEADDIM * DSTATE)
                        + (size_t)p * DSTATE + nq;
        #pragma unroll
        for (int i = 0; i < 8; i++) {
            float4 v = *(const float4*)(ps + i * 4);
            const int n = nq + i * 4;
            sT[n][p] = v.x; sT[n+1][p] = v.y; sT[n+2][p] = v.z; sT[n+3][p] = v.w;
        }
    }

    float acc[4][8];
    #pragma unroll
    for (int i = 0; i < 4; i++)
        #pragma unroll
        for (int j = 0; j < 8; j++) acc[i][j] = 0.0f;

    const float* pCbase = XC + row0 * XCW + 2176;           // C columns
    const float* pcm    = cumA + (hd * NCHUNK + c) * Q;

    for (int kp = 0; kp < 4; kp++) {                        // 4 K-panels of 32
        __syncthreads();
        {   // stage cumA-scaled C panel, coalesced in groups of 8 lanes
            const int k4 = (tid & 7) * 4;
            #pragma unroll
            for (int rep = 0; rep < 4; rep++) {
                const int t = (tid >> 3) + rep * 32;
                float4 v = *(const float4*)(pCbase + (size_t)t * XCW + kp * 32 + k4);
                const float cm = pcm[t];
                sC[k4+0][t] = v.x * cm;
                sC[k4+1][t] = v.y * cm;
                sC[k4+2][t] = v.z * cm;
                sC[k4+3][t] = v.w * cm;
            }
        }
        __syncthreads();

        // software-pipelined inner product over the 32 k of this panel
        float avA[4], bvA[8], avB[4], bvB[8];
        *(float4*)&avA[0] = *(const float4*)&sC[0][tx*4];
        *(float4*)&bvA[0] = *(const float4*)&sT[kp*32][ty*8];
        *(float4*)&bvA[4] = *(const float4*)&sT[kp*32][ty*8+4];
        for (int k = 0; k < 32; k += 2) {
            *(float4*)&avB[0] = *(const float4*)&sC[k+1][tx*4];
            *(float4*)&bvB[0] = *(const float4*)&sT[kp*32+k+1][ty*8];
            *(float4*)&bvB[4] = *(const float4*)&sT[kp*32+k+1][ty*8+4];
            #pragma unroll
            for (int i = 0; i < 4; i++)
                #pragma unroll
                for (int j = 0; j < 8; j++) acc[i][j] += avA[i] * bvA[j];
            if (k + 2 < 32) {
                *(float4*)&avA[0] = *(const float4*)&sC[k+2][tx*4];
                *(float4*)&bvA[0] = *(const float4*)&sT[kp*32+k+2][ty*8];
                *(float4*)&bvA[4] = *(const float4*)&sT[kp*32+k+2][ty*8+4];
            }
            #pragma unroll
            for (int i = 0; i < 4; i++)
                #pragma unroll
                for (int j = 0; j < 8; j++) acc[i][j] += avB[i] * bvB[j];
        }
    }

    // ---- epilogue: out = (y_pre + corr) * silu(z) ----
    #pragma unroll
    for (int i = 0; i < 4; i++) {
        const int t = tx * 4 + i;
        float* po = out + (row0 + t) * (size_t)DINNER + h * HEADDIM + ty * 8;
        const float* pz = zx + (row0 + t) * (size_t)DPROJ + h * HEADDIM + ty * 8;
        float4 y0 = *(const float4*)po;
        float4 y1 = *(const float4*)(po + 4);
        float4 z0 = *(const float4*)pz;
        float4 z1 = *(const float4*)(pz + 4);
        const float yv[8] = {y0.x,y0.y,y0.z,y0.w,y1.x,y1.y,y1.z,y1.w};
        const float zv[8] = {z0.x,z0.y,z0.z,z0.w,z1.x,z1.y,z1.z,z1.w};
        float r[8];
        #pragma unroll
        for (int j = 0; j < 8; j++) {
            const float zg = zv[j] * sigm(zv[j]);
            r[j] = (yv[j] + acc[i][j]) * zg;
        }
        *(float4*)po       = make_float4(r[0], r[1], r[2], r[3]);
        *(float4*)(po + 4) = make_float4(r[4], r[5], r[6], r[7]);
    }
}

// ---------------------------------------------------------------------------
extern "C" void kernel_launch(void* const* d_in, const int* in_sizes, int n_in,
                              void* d_out, int out_size, void* d_ws, size_t ws_size,
                              hipStream_t stream) {
    const float* zxbcdt   = (const float*)d_in[0];
    const float* conv_w   = (const float*)d_in[1];
    const float* conv_b   = (const float*)d_in[2];
    const float* dt_bias  = (const float*)d_in[3];
    const float* a_log    = (const float*)d_in[4];
    const float* d_param  = (const float*)d_in[5];
    const float* dt_scale = (const float*)d_in[6];
    const float* init_st  = (const float*)d_in[7];
    const int* dt_min_p   = (const int*)d_in[11];
    const int* dt_max_p   = (const int*)d_in[12];
    float* out = (float*)d_out;

    // workspace: XC (pad +4 rows) 37.8 + dtA 1 + SA 33.5 + cumA 0.5 MiB ~= 73 MiB
    char* ws = (char*)d_ws;
    const size_t n_bl = (size_t)BSZ * LLEN;                           // 4096
    float*  XC  = (float*)ws;  ws += (n_bl + 4) * XCW * sizeof(float);
    float2* dtA = (float2*)ws; ws += n_bl * NHEADS * sizeof(float2);
    float*  SA  = (float*)ws;
    ws += (size_t)BSZ * NHEADS * NCHUNK * HEADDIM * DSTATE * sizeof(float);
    float*  dtot = (float*)ws; ws += (size_t)BSZ * NHEADS * NCHUNK * sizeof(float);
    float*  cumA = (float*)ws;
    ws += (size_t)BSZ * NHEADS * LLEN * sizeof(float);

    pre_kernel<<<dim3((unsigned)n_bl), 256, 0, stream>>>(
        zxbcdt, conv_w, conv_b, dt_bias, a_log, dt_scale,
        dt_min_p, dt_max_p, XC, dtA);

    cum_kernel<<<dim3(NCHUNK, NHEADS, BSZ), 64, 0, stream>>>(dtA, cumA, dtot);

    scan_kernel<<<dim3(NCHUNK, NHEADS, BSZ), 256, 0, stream>>>(
        XC, dtA, d_param, SA, out);

    combine_kernel<<<dim3(NHEADS, BSZ, 4), 256, 0, stream>>>(init_st, dtot, SA);

    gate_kernel<<<dim3(NCHUNK, NHEADS, BSZ), 256, 0, stream>>>(
        zxbcdt, XC, cumA, SA, out);
}

// Round 7
// 372.948 us; speedup vs baseline: 2.8586x; 1.2800x over previous
//
#include <hip/hip_runtime.h>
#include <hip/hip_bf16.h>

#define BSZ 2
#define LLEN 2048
#define NHEADS 32
#define HEADDIM 64
#define DSTATE 128
#define DCONV 4
#define DINNER (NHEADS * HEADDIM)                  // 2048
#define DPROJ  (2 * DINNER + 2 * DSTATE + NHEADS)  // 4384
#define Q 128                                      // scan chunk length
#define NCHUNK (LLEN / Q)                          // 16
#define XCW 2304                                   // XC row: [xv 2048 | B 128 | C 128]

__device__ __forceinline__ float sigm(float x) {
    return __builtin_amdgcn_rcpf(1.0f + __expf(-x));
}

// Robust python-int scalar read (int32 bits or float32 bits).
__device__ __forceinline__ float int_scalar(const int* p) {
    int i = *p;
    if (i >= 0 && i <= 1000000) return (float)i;
    return __int_as_float(i);
}

// ---------------------------------------------------------------------------
// Kernel 1: conv+silu for ALL 2304 conv channels -> XC row [xv|B|C], plus
// dt/dA. One block per (b,l); thread handles 8 x-channels + 1 B/C channel.
// ---------------------------------------------------------------------------
__global__ __launch_bounds__(256) void pre_kernel(
    const float* __restrict__ zx, const float* __restrict__ cw,
    const float* __restrict__ cb, const float* __restrict__ dtb,
    const float* __restrict__ alog, const float* __restrict__ dts,
    const int* __restrict__ mn_p, const int* __restrict__ mx_p,
    float* __restrict__ XC, float2* __restrict__ dtA)
{
    const int bl  = blockIdx.x;            // 0 .. B*L-1
    const int b   = bl / LLEN;
    const int l   = bl % LLEN;
    const int tid = threadIdx.x;

    // ---- x channels: 8 per thread (conv rows 0..2047, zx cols DINNER+c) ----
    {
        const int c8 = tid * 8;
        float acc[8];
        {
            float4 b0 = *(const float4*)(cb + c8);
            float4 b1 = *(const float4*)(cb + c8 + 4);
            acc[0]=b0.x; acc[1]=b0.y; acc[2]=b0.z; acc[3]=b0.w;
            acc[4]=b1.x; acc[5]=b1.y; acc[6]=b1.z; acc[7]=b1.w;
        }
        float4 w[8];
        #pragma unroll
        for (int j = 0; j < 8; j++) w[j] = *(const float4*)(cw + (size_t)(c8 + j) * 4);
        #pragma unroll
        for (int k = 0; k < DCONV; k++) {
            const int lk = l - (DCONV - 1) + k;
            if (lk >= 0) {
                const float* xr = zx + ((size_t)b * LLEN + lk) * DPROJ + DINNER + c8;
                float4 v0 = *(const float4*)xr;
                float4 v1 = *(const float4*)(xr + 4);
                const float tap[8] = {v0.x,v0.y,v0.z,v0.w,v1.x,v1.y,v1.z,v1.w};
                #pragma unroll
                for (int j = 0; j < 8; j++) {
                    const float wk = (k==0) ? w[j].x : (k==1) ? w[j].y : (k==2) ? w[j].z : w[j].w;
                    acc[j] += wk * tap[j];
                }
            }
        }
        float r[8];
        #pragma unroll
        for (int j = 0; j < 8; j++) r[j] = acc[j] * sigm(acc[j]);
        float* xo = XC + (size_t)bl * XCW + c8;
        *(float4*)xo       = make_float4(r[0], r[1], r[2], r[3]);
        *(float4*)(xo + 4) = make_float4(r[4], r[5], r[6], r[7]);
    }

    // ---- B/C channel: conv row 2048+tid, zx col 4096+tid ----
    {
        const int ch = 2048 + tid;
        float a = cb[ch];
        const float4 wv = *(const float4*)(cw + (size_t)ch * 4);
        #pragma unroll
        for (int k = 0; k < DCONV; k++) {
            const int lk = l - (DCONV - 1) + k;
            if (lk >= 0) {
                const float wk = (k==0) ? wv.x : (k==1) ? wv.y : (k==2) ? wv.z : wv.w;
                a += wk * zx[((size_t)b * LLEN + lk) * DPROJ + DINNER + ch];
            }
        }
        XC[(size_t)bl * XCW + ch] = a * sigm(a);
    }

    // ---- dt / dA ----
    if (tid < NHEADS) {
        float raw = zx[(size_t)bl * DPROJ + (DPROJ - NHEADS) + tid];
        float v   = raw * dts[tid] + dtb[tid];
        float sp  = (v > 20.0f) ? v : log1pf(__expf(v));
        float dt  = fminf(fmaxf(sp, int_scalar(mn_p)), int_scalar(mx_p));
        float A   = -__expf(alog[tid]);
        dtA[(size_t)bl * NHEADS + tid] = make_float2(dt, __expf(dt * A));
    }
}

// ---------------------------------------------------------------------------
// Kernel 2: per-chunk inclusive decay cumprod cumA[t] and chunk totals dtot.
// Q=128: each lane owns 2 consecutive t.
// ---------------------------------------------------------------------------
__global__ __launch_bounds__(64) void cum_kernel(
    const float2* __restrict__ dtA, float* __restrict__ cumA,
    float* __restrict__ dtot)
{
    const int c = blockIdx.x, h = blockIdx.y, b = blockIdx.z;
    const int lane = threadIdx.x;          // 0..63
    const float2* pd = dtA + ((size_t)(b * LLEN + c * Q + lane * 2)) * NHEADS + h;
    const float a0 = pd[0].y;
    const float a1 = pd[NHEADS].y;

    float s = a0 * a1;
    #pragma unroll
    for (int off = 1; off < 64; off <<= 1) {
        float v = __shfl_up(s, off, 64);
        if (lane >= off) s *= v;
    }
    float excl = __shfl_up(s, 1, 64);
    if (lane == 0) excl = 1.0f;

    const float c0 = excl * a0, c1 = c0 * a1;
    float* pc = cumA + ((size_t)(b * NHEADS + h) * NCHUNK + c) * Q + lane * 2;
    *(float2*)pc = make_float2(c0, c1);
    if (lane == 63) dtot[(size_t)(b * NHEADS + h) * NCHUNK + c] = c1;
}

// ---------------------------------------------------------------------------
// Phase A scan: zero-init local chunk scan.
// One block per (b,h,c). Wave: 4 p-slots x 16 n-groups; each lane owns
// 4 CONSECUTIVE p (p0..p0+3) and 8 n. Halves the B/C L1 redundancy vs the
// 8-slot tile (round 6 evidence: duration invariant to occupancy -> per-CU
// L1/TA bandwidth bound on 8x-redundant B/C loads; this tile is 4x).
// x becomes one float4/lane; y written as one float4 by ng==0 lanes.
// Depth-2 ring; demand ~116 regs, under the 128-reg/4-wave budget.
// SPILL TRIPWIRE: if WRITE_SIZE >> 66 MB, allocator spilled -> (256,3).
// ---------------------------------------------------------------------------
__global__ __launch_bounds__(256, 4) void scan_kernel(
    const float* __restrict__ XC, const float2* __restrict__ dtA,
    const float* __restrict__ d_param, float* __restrict__ SA,
    float* __restrict__ out)
{
    const int c    = blockIdx.x;
    const int h    = blockIdx.y;
    const int b    = blockIdx.z;
    const int tid  = threadIdx.x;
    const int wave = tid >> 6;
    const int lane = tid & 63;
    const int ng   = lane & 15;            // n-group (low 4 bits): 16 groups x 8 n
    const int pl   = lane >> 4;            // 0..3
    const int p0   = wave * 16 + pl * 4;   // 4 consecutive p per lane
    const int n0   = ng * 8;
    const int t0   = c * Q;
    const int cx   = h * HEADDIM + p0;
    const float Dh = d_param[h];

    const float*  pB = XC + ((size_t)b * LLEN + t0) * XCW + 2048 + n0;  // C at +128
    const float*  pv = XC + ((size_t)b * LLEN + t0) * XCW + cx;
    const float2* pd = dtA + ((size_t)b * LLEN + t0) * NHEADS + h;
    float*        pw = out + ((size_t)b * LLEN + t0) * DINNER + cx;

    float st[4][8];
    #pragma unroll
    for (int j = 0; j < 4; j++)
        #pragma unroll
        for (int n = 0; n < 8; n++) st[j][n] = 0.0f;

    // depth-2 register ring for B,C,x,dtA
    float4 rb[2][2], rc[2][2], rx[2];
    float2 rda[2];
    #pragma unroll
    for (int u = 0; u < 2; u++) {
        const float* r = pB + (size_t)u * XCW;
        rb[u][0] = *(const float4*)(r);
        rb[u][1] = *(const float4*)(r + 4);
        rc[u][0] = *(const float4*)(r + 128);
        rc[u][1] = *(const float4*)(r + 132);
        rx[u]    = *(const float4*)(pv + (size_t)u * XCW);
        rda[u]   = pd[(size_t)u * NHEADS];
    }
    const float*  pn  = pB + 2 * XCW;      // B/C prefetch row (t+2)
    const float*  pxn = pv + 2 * XCW;      // x prefetch row (t+2)
    const float2* pdn = pd + 2 * NHEADS;

    auto step = [&](int u) {
        const float Bv[8] = {rb[u][0].x, rb[u][0].y, rb[u][0].z, rb[u][0].w,
                             rb[u][1].x, rb[u][1].y, rb[u][1].z, rb[u][1].w};
        const float Cv[8] = {rc[u][0].x, rc[u][0].y, rc[u][0].z, rc[u][0].w,
                             rc[u][1].x, rc[u][1].y, rc[u][1].z, rc[u][1].w};
        const float4 xv = rx[u];
        const float2 da = rda[u];

        // prefetch t+2 into slot u (unconditional; overrun lands in pad rows)
        rb[u][0] = *(const float4*)(pn);
        rb[u][1] = *(const float4*)(pn + 4);
        rc[u][0] = *(const float4*)(pn + 128);
        rc[u][1] = *(const float4*)(pn + 132);
        rx[u]    = *(const float4*)pxn;
        rda[u]   = pdn[0];
        pn += XCW; pxn += XCW; pdn += NHEADS;

        const float dAv = da.y;
        const float cf[4] = {da.x * xv.x, da.x * xv.y, da.x * xv.z, da.x * xv.w};
        float acc[4] = {0.f, 0.f, 0.f, 0.f};
        #pragma unroll
        for (int n = 0; n < 8; n++) {
            #pragma unroll
            for (int j = 0; j < 4; j++) {
                st[j][n] = dAv * st[j][n] + cf[j] * Bv[n];
                acc[j]  += st[j][n] * Cv[n];
            }
        }
        // reduce each p-dot over the 16 lanes of this pl-group
        #pragma unroll
        for (int m = 1; m <= 8; m <<= 1) {
            acc[0] += __shfl_xor(acc[0], m, 64);
            acc[1] += __shfl_xor(acc[1], m, 64);
            acc[2] += __shfl_xor(acc[2], m, 64);
            acc[3] += __shfl_xor(acc[3], m, 64);
        }

        if (ng == 0) {
            *(float4*)pw = make_float4(acc[0] + Dh * xv.x,
                                       acc[1] + Dh * xv.y,
                                       acc[2] + Dh * xv.z,
                                       acc[3] + Dh * xv.w);   // ungated y_pre
        }
        pw += DINNER;
    };

    for (int tb = 0; tb < Q; tb += 2) {
        step(0); step(1);
    }

    // store chunk-end local state: SA[p][n], p = p0+j, n = n0..n0+7
    const size_t sb = ((size_t)(b * NHEADS + h) * NCHUNK + c) * (HEADDIM * DSTATE)
                    + (size_t)p0 * DSTATE + n0;
    #pragma unroll
    for (int j = 0; j < 4; j++) {
        *(float4*)(SA + sb + (size_t)j * DSTATE)     =
            make_float4(st[j][0], st[j][1], st[j][2], st[j][3]);
        *(float4*)(SA + sb + (size_t)j * DSTATE + 4) =
            make_float4(st[j][4], st[j][5], st[j][6], st[j][7]);
    }
}

// ---------------------------------------------------------------------------
// Phase B: sequential chunk combine per (b,h). SA[c] := state ENTERING chunk c.
// Grid (NHEADS, BSZ, 4): 4 p-groups for better CU utilization.
// ---------------------------------------------------------------------------
__global__ __launch_bounds__(256) void combine_kernel(
    const float* __restrict__ init_state, const float* __restrict__ dtot,
    float* __restrict__ SA)
{
    const int h = blockIdx.x, b = blockIdx.y, pg = blockIdx.z;
    const size_t hd = (size_t)(b * NHEADS + h);
    const size_t eb = (size_t)pg * 2048 + (size_t)threadIdx.x * 8;

    const float4* pi = (const float4*)(init_state + hd * (HEADDIM * DSTATE) + eb);
    float4 r0 = pi[0], r1 = pi[1];

    for (int c = 0; c < NCHUNK; c++) {
        const float d = dtot[hd * NCHUNK + c];
        float4* ps = (float4*)(SA + (hd * NCHUNK + c) * (size_t)(HEADDIM * DSTATE) + eb);
        float4 l0 = ps[0], l1 = ps[1];
        ps[0] = r0; ps[1] = r1;
        r0.x = d * r0.x + l0.x;  r0.y = d * r0.y + l0.y;
        r0.z = d * r0.z + l0.z;  r0.w = d * r0.w + l0.w;
        r1.x = d * r1.x + l1.x;  r1.y = d * r1.y + l1.y;
        r1.z = d * r1.z + l1.z;  r1.w = d * r1.w + l1.w;
    }
}

// ---------------------------------------------------------------------------
// Phase C: cross-chunk correction as a tiled GEMM + gate epilogue.
//   corr[t,p] = (cumA[t]*C[t,:]) . Sin[p,:]   (K = DSTATE = 128)
//   out[t,p]  = (y_pre[t,p] + corr[t,p]) * silu(z[t,p])
// One block per (b,h,c): 256 threads, 4x8 register tile each (128t x 64p).
// LDS 48 KB -> 3 blocks/CU; launch_bounds(256,3) to claim that residency.
// ---------------------------------------------------------------------------
__global__ __launch_bounds__(256, 3) void gate_kernel(
    const float* __restrict__ zx, const float* __restrict__ XC,
    const float* __restrict__ cumA, const float* __restrict__ SA,
    float* __restrict__ out)
{
    __shared__ float sT[DSTATE][HEADDIM];   // Sin^T [n][p], 32 KB
    __shared__ float sC[32][Q];             // scaled C panel [k][t], 16 KB

    const int c = blockIdx.x, h = blockIdx.y, b = blockIdx.z;
    const int tid = threadIdx.x;
    const int tx = tid & 31;                // t-tile: t = tx*4 + i
    const int ty = tid >> 5;                // p-tile: p = ty*8 + j
    const size_t hd = (size_t)(b * NHEADS + h);
    const size_t row0 = (size_t)b * LLEN + c * Q;

    // ---- load Sin^T (transpose SA[p][n] -> sT[n][p]) ----
    {
        const int p  = tid >> 2;
        const int nq = (tid & 3) * 32;
        const float* ps = SA + (hd * NCHUNK + c) * (size_t)(HEADDIM * DSTATE)
                        + (size_t)p * DSTATE + nq;
        #pragma unroll
        for (int i = 0; i < 8; i++) {
            float4 v = *(const float4*)(ps + i * 4);
            const int n = nq + i * 4;
            sT[n][p] = v.x; sT[n+1][p] = v.y; sT[n+2][p] = v.z; sT[n+3][p] = v.w;
        }
    }

    float acc[4][8];
    #pragma unroll
    for (int i = 0; i < 4; i++)
        #pragma unroll
        for (int j = 0; j < 8; j++) acc[i][j] = 0.0f;

    const float* pCbase = XC + row0 * XCW + 2176;           // C columns
    const float* pcm    = cumA + (hd * NCHUNK + c) * Q;

    for (int kp = 0; kp < 4; kp++) {                        // 4 K-panels of 32
        __syncthreads();
        {   // stage cumA-scaled C panel, coalesced in groups of 8 lanes
            const int k4 = (tid & 7) * 4;
            #pragma unroll
            for (int rep = 0; rep < 4; rep++) {
                const int t = (tid >> 3) + rep * 32;
                float4 v = *(const float4*)(pCbase + (size_t)t * XCW + kp * 32 + k4);
                const float cm = pcm[t];
                sC[k4+0][t] = v.x * cm;
                sC[k4+1][t] = v.y * cm;
                sC[k4+2][t] = v.z * cm;
                sC[k4+3][t] = v.w * cm;
            }
        }
        __syncthreads();

        // software-pipelined inner product over the 32 k of this panel
        float avA[4], bvA[8], avB[4], bvB[8];
        *(float4*)&avA[0] = *(const float4*)&sC[0][tx*4];
        *(float4*)&bvA[0] = *(const float4*)&sT[kp*32][ty*8];
        *(float4*)&bvA[4] = *(const float4*)&sT[kp*32][ty*8+4];
        for (int k = 0; k < 32; k += 2) {
            *(float4*)&avB[0] = *(const float4*)&sC[k+1][tx*4];
            *(float4*)&bvB[0] = *(const float4*)&sT[kp*32+k+1][ty*8];
            *(float4*)&bvB[4] = *(const float4*)&sT[kp*32+k+1][ty*8+4];
            #pragma unroll
            for (int i = 0; i < 4; i++)
                #pragma unroll
                for (int j = 0; j < 8; j++) acc[i][j] += avA[i] * bvA[j];
            if (k + 2 < 32) {
                *(float4*)&avA[0] = *(const float4*)&sC[k+2][tx*4];
                *(float4*)&bvA[0] = *(const float4*)&sT[kp*32+k+2][ty*8];
                *(float4*)&bvA[4] = *(const float4*)&sT[kp*32+k+2][ty*8+4];
            }
            #pragma unroll
            for (int i = 0; i < 4; i++)
                #pragma unroll
                for (int j = 0; j < 8; j++) acc[i][j] += avB[i] * bvB[j];
        }
    }

    // ---- epilogue: out = (y_pre + corr) * silu(z) ----
    #pragma unroll
    for (int i = 0; i < 4; i++) {
        const int t = tx * 4 + i;
        float* po = out + (row0 + t) * (size_t)DINNER + h * HEADDIM + ty * 8;
        const float* pz = zx + (row0 + t) * (size_t)DPROJ + h * HEADDIM + ty * 8;
        float4 y0 = *(const float4*)po;
        float4 y1 = *(const float4*)(po + 4);
        float4 z0 = *(const float4*)pz;
        float4 z1 = *(const float4*)(pz + 4);
        const float yv[8] = {y0.x,y0.y,y0.z,y0.w,y1.x,y1.y,y1.z,y1.w};
        const float zv[8] = {z0.x,z0.y,z0.z,z0.w,z1.x,z1.y,z1.z,z1.w};
        float r[8];
        #pragma unroll
        for (int j = 0; j < 8; j++) {
            const float zg = zv[j] * sigm(zv[j]);
            r[j] = (yv[j] + acc[i][j]) * zg;
        }
        *(float4*)po       = make_float4(r[0], r[1], r[2], r[3]);
        *(float4*)(po + 4) = make_float4(r[4], r[5], r[6], r[7]);
    }
}

// ---------------------------------------------------------------------------
extern "C" void kernel_launch(void* const* d_in, const int* in_sizes, int n_in,
                              void* d_out, int out_size, void* d_ws, size_t ws_size,
                              hipStream_t stream) {
    const float* zxbcdt   = (const float*)d_in[0];
    const float* conv_w   = (const float*)d_in[1];
    const float* conv_b   = (const float*)d_in[2];
    const float* dt_bias  = (const float*)d_in[3];
    const float* a_log    = (const float*)d_in[4];
    const float* d_param  = (const float*)d_in[5];
    const float* dt_scale = (const float*)d_in[6];
    const float* init_st  = (const float*)d_in[7];
    const int* dt_min_p   = (const int*)d_in[11];
    const int* dt_max_p   = (const int*)d_in[12];
    float* out = (float*)d_out;

    // workspace: XC (pad +4 rows) 37.8 + dtA 1 + SA 33.5 + cumA 0.5 MiB ~= 73 MiB
    char* ws = (char*)d_ws;
    const size_t n_bl = (size_t)BSZ * LLEN;                           // 4096
    float*  XC  = (float*)ws;  ws += (n_bl + 4) * XCW * sizeof(float);
    float2* dtA = (float2*)ws; ws += n_bl * NHEADS * sizeof(float2);
    float*  SA  = (float*)ws;
    ws += (size_t)BSZ * NHEADS * NCHUNK * HEADDIM * DSTATE * sizeof(float);
    float*  dtot = (float*)ws; ws += (size_t)BSZ * NHEADS * NCHUNK * sizeof(float);
    float*  cumA = (float*)ws;
    ws += (size_t)BSZ * NHEADS * LLEN * sizeof(float);

    pre_kernel<<<dim3((unsigned)n_bl), 256, 0, stream>>>(
        zxbcdt, conv_w, conv_b, dt_bias, a_log, dt_scale,
        dt_min_p, dt_max_p, XC, dtA);

    cum_kernel<<<dim3(NCHUNK, NHEADS, BSZ), 64, 0, stream>>>(dtA, cumA, dtot);

    scan_kernel<<<dim3(NCHUNK, NHEADS, BSZ), 256, 0, stream>>>(
        XC, dtA, d_param, SA, out);

    combine_kernel<<<dim3(NHEADS, BSZ, 4), 256, 0, stream>>>(init_st, dtot, SA);

    gate_kernel<<<dim3(NCHUNK, NHEADS, BSZ), 256, 0, stream>>>(
        zxbcdt, XC, cumA, SA, out);
}